// Round 8
// baseline (102.778 us; speedup 1.0000x reference)
//
#include <hip/hip_runtime.h>

// FBSNN loss — single dispatch; producers/consumers split.
//
// Round 23 = round 22 with the producer->stage->scan serialization broken:
//   * 115 blocks: 0..24 q-producers (rows 2b,2b+1), 25..50 Y-producers
//     (rows 2(b-25),+1; row 51 skipped), 51..114 consumers (64 scan blocks,
//     cid = blk-51, paths cid*64..+63). Producers post MAGIC sentinel and
//     exit. Consumers stage dW DURING production, stage the q grid as soon
//     as q sentinels land (overlapped with the slower Y producers), then
//     Y/dY, then wave 0 scans. Critical path = slowest Y producer + yd
//     stage + scan (eval and staging no longer serialized in one block).
//   * Y/dY stored interleaved as float2 -> the scan's Y/dY taps are 4
//     aligned ds_read_b64 (8 DS ops/step total, was 12 b32 gathers).
//   * Frag build split across 8 waves (sec = wv>>1, half = wv&1).
//   * s_sleep(1) spin polls.
// Values bitwise identical to r22 (same build/eval/interp formulas, same
// grid nodes; interleaving only relocates bytes) -> same absmax.

#define NPATH   4096
#define NSTEP   50
#define DT_F    0.02f
#define SQRT_DT 0.14142136f
#define SIGMA_F 0.5f
#define INV2PI  0.15915494309189535f
#define TWOPI_F 6.28318530717958648f

#define GRID_N   128
#define GRID_INV 8.0f
#define GRID_DY  0.125f

#define NPROD_Q 25
#define NPROD_Y 26
#define NCONS   64
#define NBLK    (51 + NCONS)                // 115
#define PPB     64                          // paths per consumer block

#define QG_FLOATS  (NSTEP * GRID_N)         // 6400
#define YD_FLOATS  (2 * (NSTEP + 1) * GRID_N) // 13056 (Y,dY interleaved)

#define MAGIC 0x5AB1C0DEu

// fragment ids (16B per lane each)
#define FR_AIN(t)     (t)
#define FR_AH(L,t,kk) (4 + (L)*8 + (t)*2 + (kk))
#define FR_AOUT(kk)   (28 + (kk))
#define FR_BIN(t)     (30 + (t))
#define FR_BHD(L,t)   (34 + (L)*4 + (t))
#define FR_BOUT       46

// workspace layout (float offsets)
#define WS_DONE 0                           // 64 ints (51 used)
#define WS_QG   64                          // 6400
#define WS_YD   (WS_QG + QG_FLOATS)         // 6464
#define WS_PAIR (WS_YD + YD_FLOATS)         // 19520: 64 x {MAGIC,float} u64

// LDS layout (float offsets)
// producers: frag build area @0 (12032 floats). consumers: grids + dW.
#define L_QG    0                           // 6400
#define L_YD    QG_FLOATS                   // 6400 (+13056), byte 25600, 16B ok
#define L_DW    (L_YD + YD_FLOATS)          // 19456 (50*64)
#define SMEM_FLOATS (L_DW + NSTEP * PPB)    // 22656
#define SMEM_BYTES  (SMEM_FLOATS * 4)       // 90,624 B

typedef __attribute__((ext_vector_type(8)))  short s16x8;
typedef __attribute__((ext_vector_type(4)))  float f32x4;
typedef __attribute__((ext_vector_type(4)))  float float4v;
typedef __attribute__((ext_vector_type(2)))  float float2v;

#if __has_builtin(__builtin_amdgcn_cvt_pk_bf16_f32)
__device__ __forceinline__ unsigned pkbf(float a, float b) {
    auto r = __builtin_amdgcn_cvt_pk_bf16_f32(a, b);
    unsigned u; __builtin_memcpy(&u, &r, 4); return u;
}
#else
__device__ __forceinline__ unsigned pkbf(float a, float b) {
    unsigned ua = __float_as_uint(a), ub = __float_as_uint(b);
    ua += 0x7fffu + ((ua >> 16) & 1u);
    ub += 0x7fffu + ((ub >> 16) & 1u);
    return (ua >> 16) | (ub & 0xffff0000u);
}
#endif

__device__ __forceinline__ s16x8 frag4(unsigned a, unsigned b, unsigned c, unsigned d) {
    union { unsigned u[4]; s16x8 s; } x;
    x.u[0] = a; x.u[1] = b; x.u[2] = c; x.u[3] = d;
    return x.s;
}

__device__ __forceinline__ float sinrev(float x) {
#if __has_builtin(__builtin_amdgcn_sinf)
    return __builtin_amdgcn_sinf(x);
#else
    return __sinf(x * TWOPI_F);
#endif
}
__device__ __forceinline__ float cosrev(float x) {
#if __has_builtin(__builtin_amdgcn_cosf)
    return __builtin_amdgcn_cosf(x);
#else
    return __cosf(x * TWOPI_F);
#endif
}

__device__ __forceinline__ int slot16(int t, int r) {
    return (t < 2) ? 8 * (r >> 2) + 4 * t + (r & 3)
                   : 32 + 8 * (r >> 2) + 4 * (t - 2) + (r & 3);
}

// Build half of one section of a net's fragments straight into LDS.
// sec 0: Ain+bIn (t pair) + (half 0: Aout+bout); sec 1..3: layer (t pair).
__device__ __forceinline__ void build_half(
    int sec, int half, const float* __restrict__ Win, const float* __restrict__ bin,
    const float* __restrict__ Whid, const float* __restrict__ bhid,
    const float* __restrict__ Wout, const float* __restrict__ bo,
    int qd, int m, char* fbl)
{
    const int t0 = 2 * half;
    if (sec == 0) {
#pragma unroll
        for (int t = t0; t < t0 + 2; ++t) {
            const int uo = slot16(t, m);
            unsigned w0 = 0;
            if (qd == 0) w0 = pkbf(INV2PI * Win[uo], INV2PI * Win[64 + uo]);
            *reinterpret_cast<s16x8*>(fbl + FR_AIN(t) * 1024) = frag4(w0, 0u, 0u, 0u);
            f32x4 bi;
#pragma unroll
            for (int i = 0; i < 4; ++i) bi[i] = INV2PI * bin[slot16(t, 4 * qd + i)];
            *reinterpret_cast<f32x4*>(fbl + FR_BIN(t) * 1024) = bi;
        }
        if (half == 0) {
#pragma unroll
            for (int kk = 0; kk < 2; ++kk) {
                unsigned w[4] = {0u, 0u, 0u, 0u};
                if (m == 0) {
#pragma unroll
                    for (int j2 = 0; j2 < 4; ++j2) {
                        int e0 = 32 * kk + 8 * qd + 2 * j2;
                        w[j2] = pkbf(Wout[e0], Wout[e0 + 1]);
                    }
                }
                *reinterpret_cast<s16x8*>(fbl + FR_AOUT(kk) * 1024) = frag4(w[0], w[1], w[2], w[3]);
            }
            f32x4 bo4 = {bo[0], 0.0f, 0.0f, 0.0f};
            *reinterpret_cast<f32x4*>(fbl + FR_BOUT * 1024) = bo4;
        }
    } else {
        const int L = sec - 1;
#pragma unroll
        for (int t = t0; t < t0 + 2; ++t) {
            const int uo = slot16(t, m);
            const float* W = Whid + L * 4096 + uo;
#pragma unroll
            for (int kk = 0; kk < 2; ++kk) {
                unsigned w[4];
#pragma unroll
                for (int j2 = 0; j2 < 4; ++j2) {
                    int e0 = 32 * kk + 8 * qd + 2 * j2;
                    w[j2] = pkbf(INV2PI * W[e0 * 64], INV2PI * W[(e0 + 1) * 64]);
                }
                *reinterpret_cast<s16x8*>(fbl + FR_AH(L, t, kk) * 1024) = frag4(w[0], w[1], w[2], w[3]);
            }
            f32x4 bh;
#pragma unroll
            for (int i = 0; i < 4; ++i) bh[i] = INV2PI * bhid[L * 64 + slot16(t, 4 * qd + i)];
            *reinterpret_cast<f32x4*>(fbl + FR_BHD(L, t) * 1024) = bh;
        }
    }
}

__device__ __forceinline__ void trans16(const f32x4* C, s16x8& B0, s16x8& B1) {
    float a[4][4];
#pragma unroll
    for (int t = 0; t < 4; ++t)
#pragma unroll
        for (int i = 0; i < 4; ++i) a[t][i] = sinrev(C[t][i]);
    B0 = frag4(pkbf(a[0][0], a[0][1]), pkbf(a[0][2], a[0][3]),
               pkbf(a[1][0], a[1][1]), pkbf(a[1][2], a[1][3]));
    B1 = frag4(pkbf(a[2][0], a[2][1]), pkbf(a[2][2], a[2][3]),
               pkbf(a[3][0], a[3][1]), pkbf(a[3][2], a[3][3]));
}

__device__ __forceinline__ void trans16t(const f32x4* Cf, const f32x4* Ct,
                                         s16x8& Bf0, s16x8& Bf1,
                                         s16x8& Bt0, s16x8& Bt1)
{
    float s[4][4], d[4][4];
#pragma unroll
    for (int t = 0; t < 4; ++t)
#pragma unroll
        for (int i = 0; i < 4; ++i) {
            float cf = Cf[t][i];
            s[t][i] = sinrev(cf);
            d[t][i] = cosrev(cf) * (TWOPI_F * Ct[t][i]);
        }
    Bf0 = frag4(pkbf(s[0][0], s[0][1]), pkbf(s[0][2], s[0][3]),
                pkbf(s[1][0], s[1][1]), pkbf(s[1][2], s[1][3]));
    Bf1 = frag4(pkbf(s[2][0], s[2][1]), pkbf(s[2][2], s[2][3]),
                pkbf(s[3][0], s[3][1]), pkbf(s[3][2], s[3][3]));
    Bt0 = frag4(pkbf(d[0][0], d[0][1]), pkbf(d[0][2], d[0][3]),
                pkbf(d[1][0], d[1][1]), pkbf(d[1][2], d[1][3]));
    Bt1 = frag4(pkbf(d[2][0], d[2][1]), pkbf(d[2][2], d[2][3]),
                pkbf(d[3][0], d[3][1]), pkbf(d[3][2], d[3][3]));
}

__device__ __forceinline__ float grid_ylo(const float* __restrict__ y0p) {
    return floorf(y0p[0] * 8.0f) * 0.125f - 8.0f;
}

// forward-only eval (q-grid), frags from LDS at fbl = base + l*16
__device__ __forceinline__ float eval16_q(const char* fbl, const s16x8& Bty) {
    const f32x4 zc = {0.0f, 0.0f, 0.0f, 0.0f};
    f32x4 C[4];
#pragma unroll
    for (int t = 0; t < 4; ++t) {
        const s16x8 a  = *reinterpret_cast<const s16x8*>(fbl + FR_AIN(t) * 1024);
        const f32x4 bi = *reinterpret_cast<const f32x4*>(fbl + FR_BIN(t) * 1024);
        C[t] = __builtin_amdgcn_mfma_f32_16x16x32_bf16(a, Bty, bi, 0, 0, 0);
    }
    s16x8 B0, B1;
    trans16(C, B0, B1);
#pragma unroll
    for (int L = 0; L < 3; ++L) {
#pragma unroll
        for (int t = 0; t < 4; ++t) {
            const s16x8 a0 = *reinterpret_cast<const s16x8*>(fbl + FR_AH(L, t, 0) * 1024);
            const s16x8 a1 = *reinterpret_cast<const s16x8*>(fbl + FR_AH(L, t, 1) * 1024);
            const f32x4 bh = *reinterpret_cast<const f32x4*>(fbl + FR_BHD(L, t) * 1024);
            f32x4 c = __builtin_amdgcn_mfma_f32_16x16x32_bf16(a0, B0, bh, 0, 0, 0);
            C[t]    = __builtin_amdgcn_mfma_f32_16x16x32_bf16(a1, B1, c, 0, 0, 0);
        }
        trans16(C, B0, B1);
    }
    const s16x8 o0 = *reinterpret_cast<const s16x8*>(fbl + FR_AOUT(0) * 1024);
    const s16x8 o1 = *reinterpret_cast<const s16x8*>(fbl + FR_AOUT(1) * 1024);
    f32x4 Co = __builtin_amdgcn_mfma_f32_16x16x32_bf16(o0, B0, zc, 0, 0, 0);
    Co = __builtin_amdgcn_mfma_f32_16x16x32_bf16(o1, B1, Co, 0, 0, 0);
    return Co[0] + *reinterpret_cast<const float*>(fbl + FR_BOUT * 1024);
}

// fwd + tangent eval (Y-grid): returns Y and dY/dy at the 16 cols
__device__ __forceinline__ void eval16t(const char* fbl, const s16x8& Bty,
                                        const s16x8& Btn, float& Yv, float& dYv) {
    const f32x4 zc = {0.0f, 0.0f, 0.0f, 0.0f};
    f32x4 Cf[4], Ct[4];
#pragma unroll
    for (int t = 0; t < 4; ++t) {
        const s16x8 a  = *reinterpret_cast<const s16x8*>(fbl + FR_AIN(t) * 1024);
        const f32x4 bi = *reinterpret_cast<const f32x4*>(fbl + FR_BIN(t) * 1024);
        Cf[t] = __builtin_amdgcn_mfma_f32_16x16x32_bf16(a, Bty, bi, 0, 0, 0);
        Ct[t] = __builtin_amdgcn_mfma_f32_16x16x32_bf16(a, Btn, zc, 0, 0, 0);
    }
    s16x8 bf0, bf1, bt0, bt1;
    trans16t(Cf, Ct, bf0, bf1, bt0, bt1);
#pragma unroll
    for (int L = 0; L < 3; ++L) {
#pragma unroll
        for (int t = 0; t < 4; ++t) {
            const s16x8 a0 = *reinterpret_cast<const s16x8*>(fbl + FR_AH(L, t, 0) * 1024);
            const s16x8 a1 = *reinterpret_cast<const s16x8*>(fbl + FR_AH(L, t, 1) * 1024);
            const f32x4 bh = *reinterpret_cast<const f32x4*>(fbl + FR_BHD(L, t) * 1024);
            f32x4 c = __builtin_amdgcn_mfma_f32_16x16x32_bf16(a0, bf0, bh, 0, 0, 0);
            Cf[t]   = __builtin_amdgcn_mfma_f32_16x16x32_bf16(a1, bf1, c, 0, 0, 0);
            f32x4 z = __builtin_amdgcn_mfma_f32_16x16x32_bf16(a0, bt0, zc, 0, 0, 0);
            Ct[t]   = __builtin_amdgcn_mfma_f32_16x16x32_bf16(a1, bt1, z, 0, 0, 0);
        }
        trans16t(Cf, Ct, bf0, bf1, bt0, bt1);
    }
    const s16x8 o0 = *reinterpret_cast<const s16x8*>(fbl + FR_AOUT(0) * 1024);
    const s16x8 o1 = *reinterpret_cast<const s16x8*>(fbl + FR_AOUT(1) * 1024);
    f32x4 Cof = __builtin_amdgcn_mfma_f32_16x16x32_bf16(o0, bf0, zc, 0, 0, 0);
    Cof = __builtin_amdgcn_mfma_f32_16x16x32_bf16(o1, bf1, Cof, 0, 0, 0);
    f32x4 Cot = __builtin_amdgcn_mfma_f32_16x16x32_bf16(o0, bt0, zc, 0, 0, 0);
    Cot = __builtin_amdgcn_mfma_f32_16x16x32_bf16(o1, bt1, Cot, 0, 0, 0);
    Yv  = Cof[0] + *reinterpret_cast<const float*>(fbl + FR_BOUT * 1024);
    dYv = Cot[0];
}

// Catmull-Rom (identical formula to r16-r22)
__device__ __forceinline__ float cm4(float q0, float q1, float q2, float q3, float fr) {
    return q1 + 0.5f * fr * ((q2 - q0)
             + fr * ((2.0f * q0 - 5.0f * q1 + 4.0f * q2 - q3)
             + fr * (3.0f * (q1 - q2) + q3 - q0)));
}

// ====================== the single fused kernel ======================

extern "C" __global__ void __launch_bounds__(1024, 4)
fbsnn_one(const float* __restrict__ Y_Win, const float* __restrict__ Y_bin,
          const float* __restrict__ Y_Whid, const float* __restrict__ Y_bhid,
          const float* __restrict__ Y_Wout, const float* __restrict__ Y_bout,
          const float* __restrict__ q_Win, const float* __restrict__ q_bin,
          const float* __restrict__ q_Whid, const float* __restrict__ q_bhid,
          const float* __restrict__ q_Wout, const float* __restrict__ q_bout,
          const float* __restrict__ y0p, const float* __restrict__ dW,
          float* __restrict__ ws, float* __restrict__ out)
{
    extern __shared__ __align__(16) float sf[];

    int* done = (int*)ws;
    unsigned long long* pairs = (unsigned long long*)(ws + WS_PAIR);

    const int tid = (int)threadIdx.x;
    const int wv  = tid >> 6;
    const int l   = tid & 63;
    const int qd  = l >> 4;
    const int mm  = l & 15;
    const int blk = (int)blockIdx.x;

    const float ylo = grid_ylo(y0p);

    if (blk < 51) {
        // ================== producer block ==================
        const bool is_q = (blk < NPROD_Q);
        char* fbl = (char*)sf + l * 16;

        if (wv < 8) {
            if (is_q)
                build_half(wv >> 1, wv & 1, q_Win, q_bin, q_Whid, q_bhid,
                           q_Wout, q_bout, qd, mm, fbl);
            else
                build_half(wv >> 1, wv & 1, Y_Win, Y_bin, Y_Whid, Y_bhid,
                           Y_Wout, Y_bout, qd, mm, fbl);
        }
        __syncthreads();                                   // P1

        const int rib  = wv >> 3;
        const int colg = wv & 7;
        const int col  = 16 * colg + mm;
        const int n    = is_q ? (2 * blk + rib) : (2 * (blk - NPROD_Q) + rib);
        const bool valid = is_q ? (n < NSTEP) : (n <= NSTEP);
        if (valid) {
            const float tt = n * DT_F;
            const float yg = ylo + (float)col * GRID_DY;   // k/8: exact bf16
            const s16x8 Bty = frag4((qd == 0) ? pkbf(tt, yg) : 0u, 0u, 0u, 0u);
            if (is_q) {
                const float qv = eval16_q(fbl, Bty);
                if (qd == 0) ws[WS_QG + n * GRID_N + col] = qv;
            } else {
                const s16x8 Btn = frag4((qd == 0) ? pkbf(0.0f, 1.0f) : 0u, 0u, 0u, 0u);
                float Yv, dYv;
                eval16t(fbl, Bty, Btn, Yv, dYv);
                if (qd == 0) {
                    float2v p; p.x = Yv; p.y = dYv;
                    ((float2v*)(ws + WS_YD))[n * GRID_N + col] = p;
                }
            }
        }
        __syncthreads();                                   // P2

        if (tid == 0) {
            __threadfence();   // release: writeback of this block's rows
            __hip_atomic_store(&done[blk], (int)MAGIC, __ATOMIC_RELAXED,
                               __HIP_MEMORY_SCOPE_AGENT);
        }
        return;
    }

    // ================== consumer block ==================
    const int cid = blk - 51;
    float* qg  = sf + L_QG;
    float* dWb = sf + L_DW;
    const int ts = tid - 64;               // staging index for waves 1..15

    // stage dW slab (800 float4) while producers run
    if (wv != 0 && ts < 800) {
        const int r = ts >> 4, j4 = ts & 15;
        ((float4v*)dWb)[ts] =
            *(const float4v*)(dW + r * NPATH + cid * PPB + j4 * 4);
    }

    // wave 0: spin on q sentinels, acquire
    if (wv == 0) {
        if (l < NPROD_Q)
            while (__hip_atomic_load(&done[l], __ATOMIC_RELAXED,
                                     __HIP_MEMORY_SCOPE_AGENT) != (int)MAGIC)
                __builtin_amdgcn_s_sleep(1);
        __threadfence();
    }
    __syncthreads();                                       // C1

    // waves 1..15: stage q grid (1600 float4); wave 0: spin on Y sentinels
    if (wv != 0) {
#pragma unroll
        for (int k = 0; k < 2; ++k) {
            const int idx = ts + k * 960;
            if (idx < 1600)
                ((float4v*)qg)[idx] = ((const float4v*)(ws + WS_QG))[idx];
        }
    } else {
        if (l < NPROD_Y)
            while (__hip_atomic_load(&done[NPROD_Q + l], __ATOMIC_RELAXED,
                                     __HIP_MEMORY_SCOPE_AGENT) != (int)MAGIC)
                __builtin_amdgcn_s_sleep(1);
        __threadfence();
    }
    __syncthreads();                                       // C2

    // all waves: stage Y/dY pairs (3264 float4)
    {
#pragma unroll
        for (int k = 0; k < 4; ++k) {
            const int idx = tid + k * 1024;
            if (idx < (YD_FLOATS / 4))
                ((float4v*)(sf + L_YD))[idx] = ((const float4v*)(ws + WS_YD))[idx];
        }
    }
    __syncthreads();                                       // C3

    if (wv != 0) return;

    // ---- phase B: scan + interp + inline residuals (wave 0, 64 paths) ----
    const float2v* yd = (const float2v*)(sf + L_YD);

    float y   = y0p[0];
    float acc = 0.0f;
    float Yp = 0.0f, dYp = 0.0f, qp = 0.0f, dwp = 0.0f;

    for (int n = 0; n < NSTEP; ++n) {
        const float dwv = dWb[n * PPB + l];

        float u = (y - ylo) * GRID_INV;
        u = fminf(fmaxf(u, 1.0f), 125.999f);
        int i = (int)u;
        if (i > 125) i = 125;
        const float fr = u - (float)i;

        const float* qr = qg + n * GRID_N + i;
        const float qn = cm4(qr[-1], qr[0], qr[1], qr[2], fr);

        const float2v* yr = yd + n * GRID_N + (i - 1);
        const float2v p0 = yr[0], p1 = yr[1], p2 = yr[2], p3 = yr[3];
        const float Yn  = cm4(p0.x, p1.x, p2.x, p3.x, fr);
        const float dYn = cm4(p0.y, p1.y, p2.y, p3.y, fr);

        if (n) {   // residual for step n-1: Y_n vs Y_tilde(n-1)
            const float r = Yn - (fmaf(-qp * qp, DT_F, Yp)
                                  + (SIGMA_F * dYp) * (dwp * SQRT_DT));
            acc = fmaf(r, r, acc);
        }
        qp = qn; Yp = Yn; dYp = dYn; dwp = dwv;
        y = fmaf(qn, DT_F, y) + SIGMA_F * (dwv * SQRT_DT);
    }
    {   // terminal row 50: last residual + terminal costs
        float u = (y - ylo) * GRID_INV;
        u = fminf(fmaxf(u, 1.0f), 125.999f);
        int i = (int)u;
        if (i > 125) i = 125;
        const float fr = u - (float)i;
        const float2v* yr = yd + NSTEP * GRID_N + (i - 1);
        const float2v p0 = yr[0], p1 = yr[1], p2 = yr[2], p3 = yr[3];
        const float Y50  = cm4(p0.x, p1.x, p2.x, p3.x, fr);
        const float dY50 = cm4(p0.y, p1.y, p2.y, p3.y, fr);
        const float r = Y50 - (fmaf(-qp * qp, DT_F, Yp)
                               + (SIGMA_F * dYp) * (dwp * SQRT_DT));
        acc = fmaf(r, r, acc);
        const float r1 = Y50 - y * y;
        const float r2 = dY50 - 2.0f * y;
        acc = fmaf(r1, r1, fmaf(r2, r2, acc));
    }

#pragma unroll
    for (int off = 32; off > 0; off >>= 1) acc += __shfl_down(acc, off, 64);

    // ---- cross-block reduction via {MAGIC,float} sentinel pairs ----
    if (l == 0) {
        const unsigned long long pv =
            ((unsigned long long)MAGIC << 32) |
            (unsigned long long)__float_as_uint(acc);
        __hip_atomic_store(&pairs[cid], pv, __ATOMIC_RELAXED,
                           __HIP_MEMORY_SCOPE_AGENT);
    }
    if (cid == 0) {
        unsigned long long v;
        while ((unsigned)((v = __hip_atomic_load(&pairs[l], __ATOMIC_RELAXED,
                        __HIP_MEMORY_SCOPE_AGENT)) >> 32) != MAGIC)
            __builtin_amdgcn_s_sleep(1);
        float s = __uint_as_float((unsigned)(v & 0xffffffffu));
#pragma unroll
        for (int off = 32; off > 0; off >>= 1) s += __shfl_down(s, off, 64);
        if (l == 0) out[0] = s * (1.0f / (float)NPATH);
    }
}

// ================= host launch =================

extern "C" void kernel_launch(void* const* d_in, const int* in_sizes, int n_in,
                              void* d_out, int out_size, void* d_ws, size_t ws_size,
                              hipStream_t stream)
{
    const float* Y_Win  = (const float*)d_in[0];
    const float* Y_bin  = (const float*)d_in[1];
    const float* Y_Whid = (const float*)d_in[2];
    const float* Y_bhid = (const float*)d_in[3];
    const float* Y_Wout = (const float*)d_in[4];
    const float* Y_bout = (const float*)d_in[5];
    const float* q_Win  = (const float*)d_in[6];
    const float* q_bin  = (const float*)d_in[7];
    const float* q_Whid = (const float*)d_in[8];
    const float* q_bhid = (const float*)d_in[9];
    const float* q_Wout = (const float*)d_in[10];
    const float* q_bout = (const float*)d_in[11];
    const float* y0p    = (const float*)d_in[12];
    const float* dW     = (const float*)d_in[13];

    fbsnn_one<<<dim3(NBLK), dim3(1024), SMEM_BYTES, stream>>>(
        Y_Win, Y_bin, Y_Whid, Y_bhid, Y_Wout, Y_bout,
        q_Win, q_bin, q_Whid, q_bhid, q_Wout, q_bout,
        y0p, dW, (float*)d_ws, (float*)d_out);
}

// Round 9
// 98.498 us; speedup vs baseline: 1.0435x; 1.0435x over previous
//
#include <hip/hip_runtime.h>

// FBSNN loss — single dispatch; r22 skeleton + r23 micro-wins.
//
// Round 24 = r22 (64 uniform blocks, producers embedded — measured best at
// 100.1 vs r23's split 102.8) with r23's improvements folded in:
//   * Y/dY interleaved as float2 -> scan taps are 4 aligned ds_read_b64.
//   * Frag build split across 8 waves (sec = wv>>1, half = wv&1).
//   * s_sleep(1) spin polls.
//   * scan prefetches dW one step ahead (LDS latency under interp chain).
// Structure:
//   64 blocks x 1024. Blocks 0..24: q-producers (rows 2b,2b+1);
//   blocks 25..50: Y-producers (rows 2(b-25),+1; 51 skipped). All 64
//   blocks consume: waves 8-15 stage the dW slab during phase A; after
//   the 51-sentinel rendezvous all waves stage q + Y/dY grids -> LDS;
//   wave 0 scans 64 paths (q/Y/dY Catmull-Rom + inline residuals);
//   per-block {MAGIC,float} pair; block 0 gathers 64 pairs -> out.
// Values identical to r22/r23 (same build/eval/interp formulas, same grid
// nodes; interleaving only relocates bytes) -> same absmax.

#define NPATH   4096
#define NSTEP   50
#define DT_F    0.02f
#define SQRT_DT 0.14142136f
#define SIGMA_F 0.5f
#define INV2PI  0.15915494309189535f
#define TWOPI_F 6.28318530717958648f

#define GRID_N   128
#define GRID_INV 8.0f
#define GRID_DY  0.125f

#define NPROD_Q 25
#define NBLK    64
#define PPB     64                          // paths per block (one full wave)

#define QG_FLOATS  (NSTEP * GRID_N)         // 6400
#define YD_FLOATS  (2 * (NSTEP + 1) * GRID_N) // 13056 (Y,dY interleaved)

#define MAGIC 0x5AB1C0DEu

// fragment ids (16B per lane each)
#define FR_AIN(t)     (t)
#define FR_AH(L,t,kk) (4 + (L)*8 + (t)*2 + (kk))
#define FR_AOUT(kk)   (28 + (kk))
#define FR_BIN(t)     (30 + (t))
#define FR_BHD(L,t)   (34 + (L)*4 + (t))
#define FR_BOUT       46

// workspace layout (float offsets)
#define WS_DONE 0                           // 64 ints (51 used)
#define WS_QG   64                          // 6400
#define WS_YD   (WS_QG + QG_FLOATS)         // 6464
#define WS_PAIR (WS_YD + YD_FLOATS)         // 19520: 64 x {MAGIC,float} u64

// LDS layout (float offsets)
#define L_QG    0                           // 6400
#define L_YD    QG_FLOATS                   // 6400 (+13056)
#define L_FB    L_YD                        // build area: 12032 < 13056 ✓
#define L_DW    (L_YD + YD_FLOATS)          // 19456 (50*64)
#define SMEM_FLOATS (L_DW + NSTEP * PPB)    // 22656
#define SMEM_BYTES  (SMEM_FLOATS * 4)       // 90,624 B

typedef __attribute__((ext_vector_type(8)))  short s16x8;
typedef __attribute__((ext_vector_type(4)))  float f32x4;
typedef __attribute__((ext_vector_type(4)))  float float4v;
typedef __attribute__((ext_vector_type(2)))  float float2v;

#if __has_builtin(__builtin_amdgcn_cvt_pk_bf16_f32)
__device__ __forceinline__ unsigned pkbf(float a, float b) {
    auto r = __builtin_amdgcn_cvt_pk_bf16_f32(a, b);
    unsigned u; __builtin_memcpy(&u, &r, 4); return u;
}
#else
__device__ __forceinline__ unsigned pkbf(float a, float b) {
    unsigned ua = __float_as_uint(a), ub = __float_as_uint(b);
    ua += 0x7fffu + ((ua >> 16) & 1u);
    ub += 0x7fffu + ((ub >> 16) & 1u);
    return (ua >> 16) | (ub & 0xffff0000u);
}
#endif

__device__ __forceinline__ s16x8 frag4(unsigned a, unsigned b, unsigned c, unsigned d) {
    union { unsigned u[4]; s16x8 s; } x;
    x.u[0] = a; x.u[1] = b; x.u[2] = c; x.u[3] = d;
    return x.s;
}

__device__ __forceinline__ float sinrev(float x) {
#if __has_builtin(__builtin_amdgcn_sinf)
    return __builtin_amdgcn_sinf(x);
#else
    return __sinf(x * TWOPI_F);
#endif
}
__device__ __forceinline__ float cosrev(float x) {
#if __has_builtin(__builtin_amdgcn_cosf)
    return __builtin_amdgcn_cosf(x);
#else
    return __cosf(x * TWOPI_F);
#endif
}

__device__ __forceinline__ int slot16(int t, int r) {
    return (t < 2) ? 8 * (r >> 2) + 4 * t + (r & 3)
                   : 32 + 8 * (r >> 2) + 4 * (t - 2) + (r & 3);
}

// Build half of one section of a net's fragments straight into LDS.
__device__ __forceinline__ void build_half(
    int sec, int half, const float* __restrict__ Win, const float* __restrict__ bin,
    const float* __restrict__ Whid, const float* __restrict__ bhid,
    const float* __restrict__ Wout, const float* __restrict__ bo,
    int qd, int m, char* fbl)
{
    const int t0 = 2 * half;
    if (sec == 0) {
#pragma unroll
        for (int t = t0; t < t0 + 2; ++t) {
            const int uo = slot16(t, m);
            unsigned w0 = 0;
            if (qd == 0) w0 = pkbf(INV2PI * Win[uo], INV2PI * Win[64 + uo]);
            *reinterpret_cast<s16x8*>(fbl + FR_AIN(t) * 1024) = frag4(w0, 0u, 0u, 0u);
            f32x4 bi;
#pragma unroll
            for (int i = 0; i < 4; ++i) bi[i] = INV2PI * bin[slot16(t, 4 * qd + i)];
            *reinterpret_cast<f32x4*>(fbl + FR_BIN(t) * 1024) = bi;
        }
        if (half == 0) {
#pragma unroll
            for (int kk = 0; kk < 2; ++kk) {
                unsigned w[4] = {0u, 0u, 0u, 0u};
                if (m == 0) {
#pragma unroll
                    for (int j2 = 0; j2 < 4; ++j2) {
                        int e0 = 32 * kk + 8 * qd + 2 * j2;
                        w[j2] = pkbf(Wout[e0], Wout[e0 + 1]);
                    }
                }
                *reinterpret_cast<s16x8*>(fbl + FR_AOUT(kk) * 1024) = frag4(w[0], w[1], w[2], w[3]);
            }
            f32x4 bo4 = {bo[0], 0.0f, 0.0f, 0.0f};
            *reinterpret_cast<f32x4*>(fbl + FR_BOUT * 1024) = bo4;
        }
    } else {
        const int L = sec - 1;
#pragma unroll
        for (int t = t0; t < t0 + 2; ++t) {
            const int uo = slot16(t, m);
            const float* W = Whid + L * 4096 + uo;
#pragma unroll
            for (int kk = 0; kk < 2; ++kk) {
                unsigned w[4];
#pragma unroll
                for (int j2 = 0; j2 < 4; ++j2) {
                    int e0 = 32 * kk + 8 * qd + 2 * j2;
                    w[j2] = pkbf(INV2PI * W[e0 * 64], INV2PI * W[(e0 + 1) * 64]);
                }
                *reinterpret_cast<s16x8*>(fbl + FR_AH(L, t, kk) * 1024) = frag4(w[0], w[1], w[2], w[3]);
            }
            f32x4 bh;
#pragma unroll
            for (int i = 0; i < 4; ++i) bh[i] = INV2PI * bhid[L * 64 + slot16(t, 4 * qd + i)];
            *reinterpret_cast<f32x4*>(fbl + FR_BHD(L, t) * 1024) = bh;
        }
    }
}

__device__ __forceinline__ void trans16(const f32x4* C, s16x8& B0, s16x8& B1) {
    float a[4][4];
#pragma unroll
    for (int t = 0; t < 4; ++t)
#pragma unroll
        for (int i = 0; i < 4; ++i) a[t][i] = sinrev(C[t][i]);
    B0 = frag4(pkbf(a[0][0], a[0][1]), pkbf(a[0][2], a[0][3]),
               pkbf(a[1][0], a[1][1]), pkbf(a[1][2], a[1][3]));
    B1 = frag4(pkbf(a[2][0], a[2][1]), pkbf(a[2][2], a[2][3]),
               pkbf(a[3][0], a[3][1]), pkbf(a[3][2], a[3][3]));
}

__device__ __forceinline__ void trans16t(const f32x4* Cf, const f32x4* Ct,
                                         s16x8& Bf0, s16x8& Bf1,
                                         s16x8& Bt0, s16x8& Bt1)
{
    float s[4][4], d[4][4];
#pragma unroll
    for (int t = 0; t < 4; ++t)
#pragma unroll
        for (int i = 0; i < 4; ++i) {
            float cf = Cf[t][i];
            s[t][i] = sinrev(cf);
            d[t][i] = cosrev(cf) * (TWOPI_F * Ct[t][i]);
        }
    Bf0 = frag4(pkbf(s[0][0], s[0][1]), pkbf(s[0][2], s[0][3]),
                pkbf(s[1][0], s[1][1]), pkbf(s[1][2], s[1][3]));
    Bf1 = frag4(pkbf(s[2][0], s[2][1]), pkbf(s[2][2], s[2][3]),
                pkbf(s[3][0], s[3][1]), pkbf(s[3][2], s[3][3]));
    Bt0 = frag4(pkbf(d[0][0], d[0][1]), pkbf(d[0][2], d[0][3]),
                pkbf(d[1][0], d[1][1]), pkbf(d[1][2], d[1][3]));
    Bt1 = frag4(pkbf(d[2][0], d[2][1]), pkbf(d[2][2], d[2][3]),
                pkbf(d[3][0], d[3][1]), pkbf(d[3][2], d[3][3]));
}

__device__ __forceinline__ float grid_ylo(const float* __restrict__ y0p) {
    return floorf(y0p[0] * 8.0f) * 0.125f - 8.0f;
}

__device__ __forceinline__ float eval16_q(const char* fbl, const s16x8& Bty) {
    const f32x4 zc = {0.0f, 0.0f, 0.0f, 0.0f};
    f32x4 C[4];
#pragma unroll
    for (int t = 0; t < 4; ++t) {
        const s16x8 a  = *reinterpret_cast<const s16x8*>(fbl + FR_AIN(t) * 1024);
        const f32x4 bi = *reinterpret_cast<const f32x4*>(fbl + FR_BIN(t) * 1024);
        C[t] = __builtin_amdgcn_mfma_f32_16x16x32_bf16(a, Bty, bi, 0, 0, 0);
    }
    s16x8 B0, B1;
    trans16(C, B0, B1);
#pragma unroll
    for (int L = 0; L < 3; ++L) {
#pragma unroll
        for (int t = 0; t < 4; ++t) {
            const s16x8 a0 = *reinterpret_cast<const s16x8*>(fbl + FR_AH(L, t, 0) * 1024);
            const s16x8 a1 = *reinterpret_cast<const s16x8*>(fbl + FR_AH(L, t, 1) * 1024);
            const f32x4 bh = *reinterpret_cast<const f32x4*>(fbl + FR_BHD(L, t) * 1024);
            f32x4 c = __builtin_amdgcn_mfma_f32_16x16x32_bf16(a0, B0, bh, 0, 0, 0);
            C[t]    = __builtin_amdgcn_mfma_f32_16x16x32_bf16(a1, B1, c, 0, 0, 0);
        }
        trans16(C, B0, B1);
    }
    const s16x8 o0 = *reinterpret_cast<const s16x8*>(fbl + FR_AOUT(0) * 1024);
    const s16x8 o1 = *reinterpret_cast<const s16x8*>(fbl + FR_AOUT(1) * 1024);
    f32x4 Co = __builtin_amdgcn_mfma_f32_16x16x32_bf16(o0, B0, zc, 0, 0, 0);
    Co = __builtin_amdgcn_mfma_f32_16x16x32_bf16(o1, B1, Co, 0, 0, 0);
    return Co[0] + *reinterpret_cast<const float*>(fbl + FR_BOUT * 1024);
}

__device__ __forceinline__ void eval16t(const char* fbl, const s16x8& Bty,
                                        const s16x8& Btn, float& Yv, float& dYv) {
    const f32x4 zc = {0.0f, 0.0f, 0.0f, 0.0f};
    f32x4 Cf[4], Ct[4];
#pragma unroll
    for (int t = 0; t < 4; ++t) {
        const s16x8 a  = *reinterpret_cast<const s16x8*>(fbl + FR_AIN(t) * 1024);
        const f32x4 bi = *reinterpret_cast<const f32x4*>(fbl + FR_BIN(t) * 1024);
        Cf[t] = __builtin_amdgcn_mfma_f32_16x16x32_bf16(a, Bty, bi, 0, 0, 0);
        Ct[t] = __builtin_amdgcn_mfma_f32_16x16x32_bf16(a, Btn, zc, 0, 0, 0);
    }
    s16x8 bf0, bf1, bt0, bt1;
    trans16t(Cf, Ct, bf0, bf1, bt0, bt1);
#pragma unroll
    for (int L = 0; L < 3; ++L) {
#pragma unroll
        for (int t = 0; t < 4; ++t) {
            const s16x8 a0 = *reinterpret_cast<const s16x8*>(fbl + FR_AH(L, t, 0) * 1024);
            const s16x8 a1 = *reinterpret_cast<const s16x8*>(fbl + FR_AH(L, t, 1) * 1024);
            const f32x4 bh = *reinterpret_cast<const f32x4*>(fbl + FR_BHD(L, t) * 1024);
            f32x4 c = __builtin_amdgcn_mfma_f32_16x16x32_bf16(a0, bf0, bh, 0, 0, 0);
            Cf[t]   = __builtin_amdgcn_mfma_f32_16x16x32_bf16(a1, bf1, c, 0, 0, 0);
            f32x4 z = __builtin_amdgcn_mfma_f32_16x16x32_bf16(a0, bt0, zc, 0, 0, 0);
            Ct[t]   = __builtin_amdgcn_mfma_f32_16x16x32_bf16(a1, bt1, z, 0, 0, 0);
        }
        trans16t(Cf, Ct, bf0, bf1, bt0, bt1);
    }
    const s16x8 o0 = *reinterpret_cast<const s16x8*>(fbl + FR_AOUT(0) * 1024);
    const s16x8 o1 = *reinterpret_cast<const s16x8*>(fbl + FR_AOUT(1) * 1024);
    f32x4 Cof = __builtin_amdgcn_mfma_f32_16x16x32_bf16(o0, bf0, zc, 0, 0, 0);
    Cof = __builtin_amdgcn_mfma_f32_16x16x32_bf16(o1, bf1, Cof, 0, 0, 0);
    f32x4 Cot = __builtin_amdgcn_mfma_f32_16x16x32_bf16(o0, bt0, zc, 0, 0, 0);
    Cot = __builtin_amdgcn_mfma_f32_16x16x32_bf16(o1, bt1, Cot, 0, 0, 0);
    Yv  = Cof[0] + *reinterpret_cast<const float*>(fbl + FR_BOUT * 1024);
    dYv = Cot[0];
}

__device__ __forceinline__ float cm4(float q0, float q1, float q2, float q3, float fr) {
    return q1 + 0.5f * fr * ((q2 - q0)
             + fr * ((2.0f * q0 - 5.0f * q1 + 4.0f * q2 - q3)
             + fr * (3.0f * (q1 - q2) + q3 - q0)));
}

// ====================== the single fused kernel ======================

extern "C" __global__ void __launch_bounds__(1024, 4)
fbsnn_one(const float* __restrict__ Y_Win, const float* __restrict__ Y_bin,
          const float* __restrict__ Y_Whid, const float* __restrict__ Y_bhid,
          const float* __restrict__ Y_Wout, const float* __restrict__ Y_bout,
          const float* __restrict__ q_Win, const float* __restrict__ q_bin,
          const float* __restrict__ q_Whid, const float* __restrict__ q_bhid,
          const float* __restrict__ q_Wout, const float* __restrict__ q_bout,
          const float* __restrict__ y0p, const float* __restrict__ dW,
          float* __restrict__ ws, float* __restrict__ out)
{
    extern __shared__ __align__(16) float sf[];
    float* qg  = sf + L_QG;
    float* dWb = sf + L_DW;

    int* done = (int*)ws;
    unsigned long long* pairs = (unsigned long long*)(ws + WS_PAIR);

    const int tid = (int)threadIdx.x;
    const int wv  = tid >> 6;
    const int l   = tid & 63;
    const int qd  = l >> 4;
    const int mm  = l & 15;
    const int blk = (int)blockIdx.x;

    const bool prod = (blk < 51);
    const bool is_q = (blk < NPROD_Q);
    const float ylo = grid_ylo(y0p);

    // ---- phase A: frag build (waves 0-7) + dW slab staging (waves 8-15) ----
    if (wv < 8) {
        if (prod) {
            char* fbl = (char*)(sf + L_FB) + l * 16;
            if (is_q)
                build_half(wv >> 1, wv & 1, q_Win, q_bin, q_Whid, q_bhid,
                           q_Wout, q_bout, qd, mm, fbl);
            else
                build_half(wv >> 1, wv & 1, Y_Win, Y_bin, Y_Whid, Y_bhid,
                           Y_Wout, Y_bout, qd, mm, fbl);
        }
    } else {
        const int ts = tid - 512;          // 0..511
#pragma unroll
        for (int k = 0; k < 2; ++k) {
            const int idx = ts + k * 512;
            if (idx < 800)
                ((float4v*)dWb)[idx] =
                    *(const float4v*)(dW + (idx >> 4) * NPATH + blk * PPB + (idx & 15) * 4);
        }
    }
    __syncthreads();                                       // B1

    // ---- phase A: grid tabulation (producers: 2 rows, 8 waves per row) ----
    if (prod) {
        const char* fbl = (const char*)(sf + L_FB) + l * 16;
        const int rib  = wv >> 3;
        const int colg = wv & 7;
        const int col  = 16 * colg + mm;
        const int n    = is_q ? (2 * blk + rib) : (2 * (blk - NPROD_Q) + rib);
        const bool valid = is_q ? (n < NSTEP) : (n <= NSTEP);
        if (valid) {
            const float tt = n * DT_F;
            const float yg = ylo + (float)col * GRID_DY;   // k/8: exact bf16
            const s16x8 Bty = frag4((qd == 0) ? pkbf(tt, yg) : 0u, 0u, 0u, 0u);
            if (is_q) {
                const float qv = eval16_q(fbl, Bty);
                if (qd == 0) ws[WS_QG + n * GRID_N + col] = qv;
            } else {
                const s16x8 Btn = frag4((qd == 0) ? pkbf(0.0f, 1.0f) : 0u, 0u, 0u, 0u);
                float Yv, dYv;
                eval16t(fbl, Bty, Btn, Yv, dYv);
                if (qd == 0) {
                    float2v p; p.x = Yv; p.y = dYv;
                    ((float2v*)(ws + WS_YD))[n * GRID_N + col] = p;
                }
            }
        }
        __syncthreads();                                   // B2 (producers only)
        if (tid == 0) {
            __threadfence();   // release: writeback of this block's rows
            __hip_atomic_store(&done[blk], (int)MAGIC, __ATOMIC_RELAXED,
                               __HIP_MEMORY_SCOPE_AGENT);
        }
    }

    // ---- rendezvous: wave 0 spins on the 51 sentinels ----
    if (wv == 0) {
        if (l < NPROD_Q)
            while (__hip_atomic_load(&done[l], __ATOMIC_RELAXED,
                                     __HIP_MEMORY_SCOPE_AGENT) != (int)MAGIC)
                __builtin_amdgcn_s_sleep(1);
        if (l < 26)
            while (__hip_atomic_load(&done[NPROD_Q + l], __ATOMIC_RELAXED,
                                     __HIP_MEMORY_SCOPE_AGENT) != (int)MAGIC)
                __builtin_amdgcn_s_sleep(1);
        __threadfence();        // acquire: invalidate before staging reads
    }
    __syncthreads();                                       // B3

    // ---- stage: q + Y/dY grids ws -> LDS (4864 float4, coalesced) ----
#pragma unroll
    for (int k = 0; k < 5; ++k) {
        const int idx = tid + k * 1024;
        if (idx < (L_DW / 4))
            ((float4v*)sf)[idx] = ((const float4v*)(ws + WS_QG))[idx];
    }
    __syncthreads();                                       // B4

    if (wv != 0) return;

    // ---- phase B: scan + interp + inline residuals (wave 0, 64 paths) ----
    const float2v* yd = (const float2v*)(sf + L_YD);

    float y   = y0p[0];
    float acc = 0.0f;
    float Yp = 0.0f, dYp = 0.0f, qp = 0.0f, dwp = 0.0f;
    float dwv = dWb[l];                    // n=0 prefetch

    for (int n = 0; n < NSTEP; ++n) {
        const float dw_next = (n + 1 < NSTEP) ? dWb[(n + 1) * PPB + l] : 0.0f;

        float u = (y - ylo) * GRID_INV;
        u = fminf(fmaxf(u, 1.0f), 125.999f);
        int i = (int)u;
        if (i > 125) i = 125;
        const float fr = u - (float)i;

        const float* qr = qg + n * GRID_N + i;
        const float qn = cm4(qr[-1], qr[0], qr[1], qr[2], fr);

        const float2v* yr = yd + n * GRID_N + (i - 1);
        const float2v p0 = yr[0], p1 = yr[1], p2 = yr[2], p3 = yr[3];
        const float Yn  = cm4(p0.x, p1.x, p2.x, p3.x, fr);
        const float dYn = cm4(p0.y, p1.y, p2.y, p3.y, fr);

        if (n) {   // residual for step n-1: Y_n vs Y_tilde(n-1)
            const float r = Yn - (fmaf(-qp * qp, DT_F, Yp)
                                  + (SIGMA_F * dYp) * (dwp * SQRT_DT));
            acc = fmaf(r, r, acc);
        }
        qp = qn; Yp = Yn; dYp = dYn; dwp = dwv;
        y = fmaf(qn, DT_F, y) + SIGMA_F * (dwv * SQRT_DT);
        dwv = dw_next;
    }
    {   // terminal row 50: last residual + terminal costs
        float u = (y - ylo) * GRID_INV;
        u = fminf(fmaxf(u, 1.0f), 125.999f);
        int i = (int)u;
        if (i > 125) i = 125;
        const float fr = u - (float)i;
        const float2v* yr = yd + NSTEP * GRID_N + (i - 1);
        const float2v p0 = yr[0], p1 = yr[1], p2 = yr[2], p3 = yr[3];
        const float Y50  = cm4(p0.x, p1.x, p2.x, p3.x, fr);
        const float dY50 = cm4(p0.y, p1.y, p2.y, p3.y, fr);
        const float r = Y50 - (fmaf(-qp * qp, DT_F, Yp)
                               + (SIGMA_F * dYp) * (dwp * SQRT_DT));
        acc = fmaf(r, r, acc);
        const float r1 = Y50 - y * y;
        const float r2 = dY50 - 2.0f * y;
        acc = fmaf(r1, r1, fmaf(r2, r2, acc));
    }

#pragma unroll
    for (int off = 32; off > 0; off >>= 1) acc += __shfl_down(acc, off, 64);

    // ---- cross-block reduction via {MAGIC,float} sentinel pairs ----
    if (l == 0) {
        const unsigned long long pv =
            ((unsigned long long)MAGIC << 32) |
            (unsigned long long)__float_as_uint(acc);
        __hip_atomic_store(&pairs[blk], pv, __ATOMIC_RELAXED,
                           __HIP_MEMORY_SCOPE_AGENT);
    }
    if (blk == 0) {
        unsigned long long v;
        while ((unsigned)((v = __hip_atomic_load(&pairs[l], __ATOMIC_RELAXED,
                        __HIP_MEMORY_SCOPE_AGENT)) >> 32) != MAGIC)
            __builtin_amdgcn_s_sleep(1);
        float s = __uint_as_float((unsigned)(v & 0xffffffffu));
#pragma unroll
        for (int off = 32; off > 0; off >>= 1) s += __shfl_down(s, off, 64);
        if (l == 0) out[0] = s * (1.0f / (float)NPATH);
    }
}

// ================= host launch =================

extern "C" void kernel_launch(void* const* d_in, const int* in_sizes, int n_in,
                              void* d_out, int out_size, void* d_ws, size_t ws_size,
                              hipStream_t stream)
{
    const float* Y_Win  = (const float*)d_in[0];
    const float* Y_bin  = (const float*)d_in[1];
    const float* Y_Whid = (const float*)d_in[2];
    const float* Y_bhid = (const float*)d_in[3];
    const float* Y_Wout = (const float*)d_in[4];
    const float* Y_bout = (const float*)d_in[5];
    const float* q_Win  = (const float*)d_in[6];
    const float* q_bin  = (const float*)d_in[7];
    const float* q_Whid = (const float*)d_in[8];
    const float* q_bhid = (const float*)d_in[9];
    const float* q_Wout = (const float*)d_in[10];
    const float* q_bout = (const float*)d_in[11];
    const float* y0p    = (const float*)d_in[12];
    const float* dW     = (const float*)d_in[13];

    fbsnn_one<<<dim3(NBLK), dim3(1024), SMEM_BYTES, stream>>>(
        Y_Win, Y_bin, Y_Whid, Y_bhid, Y_Wout, Y_bout,
        q_Win, q_bin, q_Whid, q_bhid, q_Wout, q_bout,
        y0p, dW, (float*)d_ws, (float*)d_out);
}